// Round 5
// baseline (301.733 us; speedup 1.0000x reference)
//
#include <hip/hip_runtime.h>
#include <cstdint>

// Fully-fused GRU: B=2048, T=256, F=64, H=32. fp32 in/out. ONE kernel.
// 1024 blocks x 256 thr = 4 waves/block, ~4 blocks/CU => 16 waves/CU = 4/SIMD
// (the round-4 kernel had 1 wave/SIMD and ~600cy/step of exposed latency).
//   waves 2,3 (producers): each stages ONE batch. Group = 16 steps = 16 MFMA
//     cols. ring x-loads, hi/lo bf16 split, 24 x-proj MFMAs/group, write LDS
//     (double-buffered, [step][gate] layout, col stride 104 floats), one
//     group ahead of the chain.
//   waves 0,1 (chains): each runs ONE batch; all 16 MFMA cols are replicas.
//     Per step: 6 hh MFMAs (A=W_hh K-permuted, B=h bf16, C-init = folded
//     biases); lane computes acts for dim pair (q*4+(m&3), +16) (dup over
//     m>>2), B-frag all-gather = 4 x v_mov_dpp quad_perm (pure VALU).
//     xp read as 24 scalar ds_read_b32 per 4-step chunk (low VGPR).
//   Barriers: raw s_barrier + lgkmcnt(0) only (17 total) — producers' HBM
//   prefetch (1 group = 16 steps ahead) stays in flight across barriers.

#define TSEQ 256
#define CSTRIDE 104                                // floats per col (16B aligned)
#define NGRP 16                                    // 16 groups x 16 steps

typedef __attribute__((ext_vector_type(8))) short bf16x8;
typedef __attribute__((ext_vector_type(4))) float f32x4;
union BF8 { unsigned u[4]; bf16x8 v; };

__device__ __forceinline__ unsigned bfr(float f) {            // bf16 RNE in hi16
    unsigned u = __float_as_uint(f);
    return u + 0x7fffu + ((u >> 16) & 1u);
}
__device__ __forceinline__ unsigned packhi(unsigned a, unsigned b) {
    return __builtin_amdgcn_perm(b, a, 0x07060302u);          // hi16(a)|hi16(b)<<16
}
// 8 fp32 -> hi (truncated bf16) + lo (bf16 of residual): 3-term-quality products
__device__ __forceinline__ void cvt2(const float4& f0, const float4& f1,
                                     bf16x8& hi, bf16x8& lo) {
    float f[8] = {f0.x,f0.y,f0.z,f0.w, f1.x,f1.y,f1.z,f1.w};
    BF8 H, L;
    #pragma unroll
    for (int d = 0; d < 4; ++d) {
        float a = f[2*d], b = f[2*d+1];
        unsigned ua = __float_as_uint(a), ub = __float_as_uint(b);
        float ra = a - __uint_as_float(ua & 0xffff0000u);
        float rb = b - __uint_as_float(ub & 0xffff0000u);
        H.u[d] = packhi(ua, ub);
        L.u[d] = packhi(bfr(ra), bfr(rb));
    }
    hi = H.v; lo = L.v;
}
__device__ __forceinline__ float sel4(f32x4 v, int u) {
    float a = (u & 1) ? v[1] : v[0];
    float b = (u & 1) ? v[3] : v[2];
    return (u & 2) ? b : a;
}
__device__ __forceinline__ float sigx(float v) {
    return __builtin_amdgcn_rcpf(1.f + exp2f(-1.4426950408889634f * v));
}
__device__ __forceinline__ float tanhx(float v) {
    float e = exp2f(-2.8853900817779268f * fabsf(v));
    return copysignf((1.f - e) * __builtin_amdgcn_rcpf(1.f + e), v);
}

#define MFMA16(A, B, C) __builtin_amdgcn_mfma_f32_16x16x32_bf16((A), (B), (C), 0, 0, 0)

// quad_perm broadcast of lane w within each aligned 4-lane quad (pure VALU).
#define QBCAST(x, w) ((unsigned)__builtin_amdgcn_update_dpp( \
        0, (int)(x), ((w) | ((w)<<2) | ((w)<<4) | ((w)<<6)), 0xf, 0xf, true))

// barrier WITHOUT the compiler's vmcnt(0) drain: producers' in-flight HBM
// prefetch (needed a full group later) survives the sync.
__device__ __forceinline__ void barrier_nodrain() {
    asm volatile("s_waitcnt lgkmcnt(0)" ::: "memory");
    __builtin_amdgcn_s_barrier();
    asm volatile("" ::: "memory");
}

__global__ __launch_bounds__(256, 4)
void gru_fused(const float* __restrict__ x, const float* __restrict__ W_ih,
               const float* __restrict__ W_hh, const float* __restrict__ b_ih,
               const float* __restrict__ b_hh, const float* __restrict__ W_head,
               const float* __restrict__ b_head, float* __restrict__ out)
{
    // [buf][pair][step*CSTRIDE + nt*16 + q*4 + r]; step = col index in group
    __shared__ float xsh[2][2][16 * CSTRIDE];
    const int tid  = threadIdx.x;
    const int wid  = tid >> 6;                     // 0,1 = chain; 2,3 = producer
    const int lane = tid & 63;
    const int m = lane & 15, q = lane >> 4;
    const int b0 = blockIdx.x * 2;

    if (wid >= 2) {
        // ===================== producer (serves chain pq) =====================
        const int pq = wid - 2;
        bf16x8 Aih[6][2];
        #pragma unroll
        for (int nt = 0; nt < 6; ++nt)
            #pragma unroll
            for (int c = 0; c < 2; ++c) {
                const float* wp = W_ih + (nt*16 + m)*64 + c*32 + q*8;
                BF8 t;
                #pragma unroll
                for (int d = 0; d < 4; ++d) t.u[d] = packhi(bfr(wp[2*d]), bfr(wp[2*d+1]));
                Aih[nt][c] = t.v;
            }
        float4 ring[4];
        // col m = step-in-group m of batch b0+pq; lane's K-slice cols q*8..+7, +32
        const float* xcol = x + ((size_t)(b0 + pq)*TSEQ + m)*64 + q*8;
        auto ldring = [&](int grp) {
            const float* p = xcol + grp*1024;      // 16 steps * 64 floats
            ring[0] = ((const float4*)p)[0];        ring[1] = ((const float4*)p)[1];
            ring[2] = ((const float4*)(p+32))[0];   ring[3] = ((const float4*)(p+32))[1];
        };
        auto projwrite = [&](int buf) {            // ring -> x-proj -> LDS[buf]
            bf16x8 Xh0, Xl0, Xh1, Xl1;
            cvt2(ring[0], ring[1], Xh0, Xl0);
            cvt2(ring[2], ring[3], Xh1, Xl1);
            #pragma unroll
            for (int nt = 0; nt < 6; ++nt) {
                f32x4 a = MFMA16(Aih[nt][0], Xh0, ((f32x4){0.f,0.f,0.f,0.f}));
                a = MFMA16(Aih[nt][0], Xl0, a);
                a = MFMA16(Aih[nt][1], Xh1, a);
                a = MFMA16(Aih[nt][1], Xl1, a);
                *(f32x4*)&xsh[buf][pq][m*CSTRIDE + nt*16 + q*4] = a;   // 16B aligned
            }
        };
        ldring(0);
        projwrite(0);                              // group-0 data into buf 0
        ldring(1);
        barrier_nodrain();                         // buf0 ready
        for (int g = 0; g < NGRP; ++g) {
            if (g < NGRP - 1) {
                projwrite((g + 1) & 1);            // chain is in buf[g&1]
                ldring(g + 2 < NGRP ? g + 2 : NGRP - 1);
            }
            barrier_nodrain();
        }
    } else {
        // ===================== chain (batch b0+cq) =====================
        const int cq = wid;
        const int u = m & 3;                       // dim replica within quad
        // ---- W_hh A-frags, K-permuted: pos p=q*8+j <-> dim (p>>1)+16*(p&1)
        bf16x8 Awh[6];
        #pragma unroll
        for (int nt = 0; nt < 6; ++nt) {
            const float* wp = W_hh + (nt*16 + m)*32;
            BF8 t;
            #pragma unroll
            for (int d = 0; d < 4; ++d) {
                int dd = q*4 + d;
                t.u[d] = packhi(bfr(wp[dd]), bfr(wp[dd + 16]));
            }
            Awh[nt] = t.v;
        }
        // ---- biases: C-init vectors (component reg <-> gate nt*16+q*4+reg)
        f32x4 FRZ[4], BN0, BN1;
        #pragma unroll
        for (int nt = 0; nt < 4; ++nt) {
            f32x4 t;
            #pragma unroll
            for (int r = 0; r < 4; ++r) { int g = nt*16 + q*4 + r; t[r] = b_ih[g] + b_hh[g]; }
            FRZ[nt] = t;
        }
        #pragma unroll
        for (int r = 0; r < 4; ++r) { BN0[r] = b_hh[64+q*4+r]; BN1[r] = b_hh[80+q*4+r]; }
        const float fn0 = b_ih[64 + q*4 + u], fn1 = b_ih[80 + q*4 + u];

        unsigned Hd[4] = {0u, 0u, 0u, 0u};         // h B-frag dwords (bf16 pairs)
        float hOL = 0.f, hOH = 0.f;                // own h dims (q*4+u, +16), fp32
        barrier_nodrain();                         // buf0 ready

        for (int g = 0; g < NGRP; ++g) {
            const int cbuf = g & 1;
            #pragma unroll
            for (int ch = 0; ch < 4; ++ch) {       // 4 chunks of 4 steps
                // chunk's x-pre scalars: 24 ds_read_b32, off the dep chain
                float xp[4][6];
                #pragma unroll
                for (int s = 0; s < 4; ++s) {
                    const float* rp = &xsh[cbuf][cq][(ch*4 + s)*CSTRIDE + q*4 + u];
                    #pragma unroll
                    for (int nt = 0; nt < 6; ++nt) xp[s][nt] = rp[nt*16];
                }
                #pragma unroll
                for (int s = 0; s < 4; ++s) {
                    BF8 bh; bh.u[0]=Hd[0]; bh.u[1]=Hd[1]; bh.u[2]=Hd[2]; bh.u[3]=Hd[3];
                    f32x4 a0 = MFMA16(Awh[0], bh.v, FRZ[0]);
                    f32x4 a1 = MFMA16(Awh[1], bh.v, FRZ[1]);
                    f32x4 a2 = MFMA16(Awh[2], bh.v, FRZ[2]);
                    f32x4 a3 = MFMA16(Awh[3], bh.v, FRZ[3]);
                    f32x4 a4 = MFMA16(Awh[4], bh.v, BN0);
                    f32x4 a5 = MFMA16(Awh[5], bh.v, BN1);

                    float r0 = sigx(xp[s][0] + sel4(a0, u));
                    float r1 = sigx(xp[s][1] + sel4(a1, u));
                    float z0 = sigx(xp[s][2] + sel4(a2, u));
                    float z1 = sigx(xp[s][3] + sel4(a3, u));
                    float t0 = tanhx(xp[s][4] + fn0 + r0 * sel4(a4, u));
                    float t1 = tanhx(xp[s][5] + fn1 + r1 * sel4(a5, u));
                    float hNL = t0 + z0 * (hOL - t0);
                    float hNH = t1 + z1 * (hOH - t1);
                    hOL = hNL; hOH = hNH;

                    // B-frag all-gather within the 4-lane replica quad (VALU).
                    unsigned pk = packhi(bfr(hNL), bfr(hNH));
                    Hd[0] = QBCAST(pk, 0);
                    Hd[1] = QBCAST(pk, 1);
                    Hd[2] = QBCAST(pk, 2);
                    Hd[3] = QBCAST(pk, 3);
                }
            }
            barrier_nodrain();
        }

        // ---- head: lane holds fp32 h dims (q*4+u, +16); dup over lane bits 2,3
        float v = hOL * W_head[q*4 + u] + hOH * W_head[16 + q*4 + u];
        v += __shfl_xor(v, 1, 64);                 // sum over u (lane bits 0,1)
        v += __shfl_xor(v, 2, 64);
        v += __shfl_xor(v, 16, 64);                // sum over q (lane bits 4,5)
        v += __shfl_xor(v, 32, 64);
        if (lane == 0) out[b0 + cq] = sigx(v + b_head[0]);
    }
}

extern "C" void kernel_launch(void* const* d_in, const int* in_sizes, int n_in,
                              void* d_out, int out_size, void* d_ws, size_t ws_size,
                              hipStream_t stream)
{
    const float* x      = (const float*)d_in[0];
    const float* W_ih   = (const float*)d_in[1];
    const float* W_hh   = (const float*)d_in[2];
    const float* b_ih   = (const float*)d_in[3];
    const float* b_hh   = (const float*)d_in[4];
    const float* W_head = (const float*)d_in[5];
    const float* b_head = (const float*)d_in[6];
    float* out = (float*)d_out;

    gru_fused<<<1024, 256, 0, stream>>>(x, W_ih, W_hh, b_ih, b_hh,
                                        W_head, b_head, out);
}

// Round 6
// 300.360 us; speedup vs baseline: 1.0046x; 1.0046x over previous
//
#include <hip/hip_runtime.h>
#include <cstdint>

// Fully-fused GRU: B=2048, T=256, F=64, H=32. fp32 in/out. ONE kernel.
// 256 blocks x 128 thr = 2 waves/block (1 chain + 1 producer), 8 batches/block.
// Round-4 post-mortem: 4-batch chain waves are work-optimal (6 MFMA/step) but
// at 1 wave/SIMD ~500cy/step of MFMA/trans latency was exposed (890cy/step
// measured vs ~350 issue). Round-5 showed occupancy-via-narrower-waves
// quadruples work. Fix: 2-WAY CHAIN INTERLEAVE — each chain wave runs TWO
// independent 4-batch GRU sets (A=batches 0-3, B=4-7), alternating per step,
// so set A's MFMA/trans latency hides under set B's issue stream (T15).
//   producer wave: stages x-proj for both sets, one group (4 steps) ahead,
//     double-buffered LDS, conflict-free layout. ~190cy/step < chain ~270.
//   chain wave: per step per set: 6 hh MFMAs (A=W_hh K-permuted, B=h bf16,
//     C-init = folded biases), acts split across replica quad (lane u owns
//     dims q*4+u, +16 of batch m>>2), B-frag all-gather = 4x v_mov_dpp
//     quad_perm (pure VALU, zero lgkm on the chain). Head fused.
//   Barriers: raw s_barrier + lgkmcnt(0) only — producer HBM prefetch stays
//   in flight across barriers. Per-batch numerics identical to round 4.

#define TSEQ 256
#define CSTRIDE 104                                // floats per col (16B aligned)

typedef __attribute__((ext_vector_type(8))) short bf16x8;
typedef __attribute__((ext_vector_type(4))) float f32x4;
union BF8 { unsigned u[4]; bf16x8 v; };

__device__ __forceinline__ unsigned bfr(float f) {            // bf16 RNE in hi16
    unsigned u = __float_as_uint(f);
    return u + 0x7fffu + ((u >> 16) & 1u);
}
__device__ __forceinline__ unsigned packhi(unsigned a, unsigned b) {
    return __builtin_amdgcn_perm(b, a, 0x07060302u);          // hi16(a)|hi16(b)<<16
}
// 8 fp32 -> hi (truncated bf16) + lo (bf16 of residual): 3-term-quality products
__device__ __forceinline__ void cvt2(const float4& f0, const float4& f1,
                                     bf16x8& hi, bf16x8& lo) {
    float f[8] = {f0.x,f0.y,f0.z,f0.w, f1.x,f1.y,f1.z,f1.w};
    BF8 H, L;
    #pragma unroll
    for (int d = 0; d < 4; ++d) {
        float a = f[2*d], b = f[2*d+1];
        unsigned ua = __float_as_uint(a), ub = __float_as_uint(b);
        float ra = a - __uint_as_float(ua & 0xffff0000u);
        float rb = b - __uint_as_float(ub & 0xffff0000u);
        H.u[d] = packhi(ua, ub);
        L.u[d] = packhi(bfr(ra), bfr(rb));
    }
    hi = H.v; lo = L.v;
}
__device__ __forceinline__ float sel4(f32x4 v, int u) {
    float a = (u & 1) ? v[1] : v[0];
    float b = (u & 1) ? v[3] : v[2];
    return (u & 2) ? b : a;
}
__device__ __forceinline__ float sigx(float v) {
    return __builtin_amdgcn_rcpf(1.f + exp2f(-1.4426950408889634f * v));
}
__device__ __forceinline__ float tanhx(float v) {
    float e = exp2f(-2.8853900817779268f * fabsf(v));
    return copysignf((1.f - e) * __builtin_amdgcn_rcpf(1.f + e), v);
}

#define MFMA16(A, B, C) __builtin_amdgcn_mfma_f32_16x16x32_bf16((A), (B), (C), 0, 0, 0)

// quad_perm broadcast of lane w within each aligned 4-lane quad (pure VALU).
#define QBCAST(x, w) ((unsigned)__builtin_amdgcn_update_dpp( \
        0, (int)(x), ((w) | ((w)<<2) | ((w)<<4) | ((w)<<6)), 0xf, 0xf, true))

// barrier WITHOUT the compiler's vmcnt(0) drain: producer's in-flight HBM
// prefetch (needed a full group later) survives the sync.
__device__ __forceinline__ void barrier_nodrain() {
    asm volatile("s_waitcnt lgkmcnt(0)" ::: "memory");
    __builtin_amdgcn_s_barrier();
    asm volatile("" ::: "memory");
}

__global__ __launch_bounds__(128, 1)
void gru_fused(const float* __restrict__ x, const float* __restrict__ W_ih,
               const float* __restrict__ W_hh, const float* __restrict__ b_ih,
               const float* __restrict__ b_hh, const float* __restrict__ W_head,
               const float* __restrict__ b_head, float* __restrict__ out)
{
    // [buf][set][col*CSTRIDE + nt*16 + q*4 + r]; col = batch + 4*step
    __shared__ float xsh[2][2][16 * CSTRIDE];
    const int tid  = threadIdx.x;
    const int wid  = tid >> 6;                     // 0 = chain, 1 = producer
    const int lane = tid & 63;
    const int m = lane & 15, q = lane >> 4;
    const int b0 = blockIdx.x * 8;

    if (wid == 1) {
        // ============ producer: stages sets A (b0..b0+3) and B (b0+4..b0+7) ===
        const int bq = m & 3, u = m >> 2;          // col m = (batch bq, step u)
        bf16x8 Aih[6][2];
        #pragma unroll
        for (int nt = 0; nt < 6; ++nt)
            #pragma unroll
            for (int c = 0; c < 2; ++c) {
                const float* wp = W_ih + (nt*16 + m)*64 + c*32 + q*8;
                BF8 t;
                #pragma unroll
                for (int d = 0; d < 4; ++d) t.u[d] = packhi(bfr(wp[2*d]), bfr(wp[2*d+1]));
                Aih[nt][c] = t.v;
            }
        float4 ringA[4], ringB[4];
        const float* xcolA = x + ((size_t)(b0 + bq)*TSEQ + u)*64 + q*8;
        const float* xcolB = x + ((size_t)(b0 + 4 + bq)*TSEQ + u)*64 + q*8;
        auto ldring = [&](int grp) {
            const float* pA = xcolA + grp*256;     // 4 steps * 64 floats
            ringA[0] = ((const float4*)pA)[0];        ringA[1] = ((const float4*)pA)[1];
            ringA[2] = ((const float4*)(pA+32))[0];   ringA[3] = ((const float4*)(pA+32))[1];
            const float* pB = xcolB + grp*256;
            ringB[0] = ((const float4*)pB)[0];        ringB[1] = ((const float4*)pB)[1];
            ringB[2] = ((const float4*)(pB+32))[0];   ringB[3] = ((const float4*)(pB+32))[1];
        };
        auto projwrite = [&](int buf) {            // rings -> x-proj -> LDS[buf]
            bf16x8 Xh0, Xl0, Xh1, Xl1;
            cvt2(ringA[0], ringA[1], Xh0, Xl0);
            cvt2(ringA[2], ringA[3], Xh1, Xl1);
            #pragma unroll
            for (int nt = 0; nt < 6; ++nt) {
                f32x4 a = MFMA16(Aih[nt][0], Xh0, ((f32x4){0.f,0.f,0.f,0.f}));
                a = MFMA16(Aih[nt][0], Xl0, a);
                a = MFMA16(Aih[nt][1], Xh1, a);
                a = MFMA16(Aih[nt][1], Xl1, a);
                *(f32x4*)&xsh[buf][0][m*CSTRIDE + nt*16 + q*4] = a;
            }
            cvt2(ringB[0], ringB[1], Xh0, Xl0);
            cvt2(ringB[2], ringB[3], Xh1, Xl1);
            #pragma unroll
            for (int nt = 0; nt < 6; ++nt) {
                f32x4 a = MFMA16(Aih[nt][0], Xh0, ((f32x4){0.f,0.f,0.f,0.f}));
                a = MFMA16(Aih[nt][0], Xl0, a);
                a = MFMA16(Aih[nt][1], Xh1, a);
                a = MFMA16(Aih[nt][1], Xl1, a);
                *(f32x4*)&xsh[buf][1][m*CSTRIDE + nt*16 + q*4] = a;
            }
        };
        ldring(0);
        projwrite(0);                              // group-0 data into buf 0
        ldring(1);
        barrier_nodrain();                         // buf0 ready
        for (int g = 0; g < 64; ++g) {
            if (g < 63) {
                projwrite((g + 1) & 1);            // chain is in buf[g&1]
                ldring(g + 2 < 64 ? g + 2 : 63);
            }
            barrier_nodrain();
        }
    } else {
        // ============ chain: TWO interleaved 4-batch sets ============
        const int bq = m >> 2, u = m & 3;          // replicas = consecutive lanes
        // ---- W_hh A-frags, K-permuted: pos p=q*8+j <-> dim (p>>1)+16*(p&1)
        bf16x8 Awh[6];
        #pragma unroll
        for (int nt = 0; nt < 6; ++nt) {
            const float* wp = W_hh + (nt*16 + m)*32;
            BF8 t;
            #pragma unroll
            for (int d = 0; d < 4; ++d) {
                int dd = q*4 + d;
                t.u[d] = packhi(bfr(wp[dd]), bfr(wp[dd + 16]));
            }
            Awh[nt] = t.v;
        }
        // ---- biases: C-init vectors (component reg <-> gate nt*16+q*4+reg)
        f32x4 FRZ[4], BN0, BN1;
        #pragma unroll
        for (int nt = 0; nt < 4; ++nt) {
            f32x4 t;
            #pragma unroll
            for (int r = 0; r < 4; ++r) { int g = nt*16 + q*4 + r; t[r] = b_ih[g] + b_hh[g]; }
            FRZ[nt] = t;
        }
        #pragma unroll
        for (int r = 0; r < 4; ++r) { BN0[r] = b_hh[64+q*4+r]; BN1[r] = b_hh[80+q*4+r]; }
        const float fn0 = b_ih[64 + q*4 + u], fn1 = b_ih[80 + q*4 + u];

        unsigned HdA[4] = {0u,0u,0u,0u}, HdB[4] = {0u,0u,0u,0u};
        float hAL = 0.f, hAH = 0.f, hBL = 0.f, hBH = 0.f;
        barrier_nodrain();                         // buf0 ready

        for (int g = 0; g < 64; ++g) {
            const int cbuf = g & 1;
            // group's x-pre scalars for BOTH sets: 48 ds_read_b32, off-chain
            float xpA[4][6], xpB[4][6];
            #pragma unroll
            for (int s = 0; s < 4; ++s) {
                const float* rpA = &xsh[cbuf][0][(bq + 4*s)*CSTRIDE + q*4 + u];
                const float* rpB = &xsh[cbuf][1][(bq + 4*s)*CSTRIDE + q*4 + u];
                #pragma unroll
                for (int nt = 0; nt < 6; ++nt) { xpA[s][nt] = rpA[nt*16]; xpB[s][nt] = rpB[nt*16]; }
            }
            #pragma unroll
            for (int s = 0; s < 4; ++s) {
                // issue both sets' MFMAs back-to-back: B's issue hides A's latency
                BF8 bhA; bhA.u[0]=HdA[0]; bhA.u[1]=HdA[1]; bhA.u[2]=HdA[2]; bhA.u[3]=HdA[3];
                f32x4 aA0 = MFMA16(Awh[0], bhA.v, FRZ[0]);
                f32x4 aA1 = MFMA16(Awh[1], bhA.v, FRZ[1]);
                f32x4 aA2 = MFMA16(Awh[2], bhA.v, FRZ[2]);
                f32x4 aA3 = MFMA16(Awh[3], bhA.v, FRZ[3]);
                f32x4 aA4 = MFMA16(Awh[4], bhA.v, BN0);
                f32x4 aA5 = MFMA16(Awh[5], bhA.v, BN1);
                BF8 bhB; bhB.u[0]=HdB[0]; bhB.u[1]=HdB[1]; bhB.u[2]=HdB[2]; bhB.u[3]=HdB[3];
                f32x4 aB0 = MFMA16(Awh[0], bhB.v, FRZ[0]);
                f32x4 aB1 = MFMA16(Awh[1], bhB.v, FRZ[1]);
                f32x4 aB2 = MFMA16(Awh[2], bhB.v, FRZ[2]);
                f32x4 aB3 = MFMA16(Awh[3], bhB.v, FRZ[3]);
                f32x4 aB4 = MFMA16(Awh[4], bhB.v, BN0);
                f32x4 aB5 = MFMA16(Awh[5], bhB.v, BN1);

                {   // set A acts (identical numerics to round 4)
                    float r0 = sigx(xpA[s][0] + sel4(aA0, u));
                    float r1 = sigx(xpA[s][1] + sel4(aA1, u));
                    float z0 = sigx(xpA[s][2] + sel4(aA2, u));
                    float z1 = sigx(xpA[s][3] + sel4(aA3, u));
                    float t0 = tanhx(xpA[s][4] + fn0 + r0 * sel4(aA4, u));
                    float t1 = tanhx(xpA[s][5] + fn1 + r1 * sel4(aA5, u));
                    float hNL = t0 + z0 * (hAL - t0);
                    float hNH = t1 + z1 * (hAH - t1);
                    hAL = hNL; hAH = hNH;
                    unsigned pk = packhi(bfr(hNL), bfr(hNH));
                    HdA[0] = QBCAST(pk, 0);
                    HdA[1] = QBCAST(pk, 1);
                    HdA[2] = QBCAST(pk, 2);
                    HdA[3] = QBCAST(pk, 3);
                }
                {   // set B acts
                    float r0 = sigx(xpB[s][0] + sel4(aB0, u));
                    float r1 = sigx(xpB[s][1] + sel4(aB1, u));
                    float z0 = sigx(xpB[s][2] + sel4(aB2, u));
                    float z1 = sigx(xpB[s][3] + sel4(aB3, u));
                    float t0 = tanhx(xpB[s][4] + fn0 + r0 * sel4(aB4, u));
                    float t1 = tanhx(xpB[s][5] + fn1 + r1 * sel4(aB5, u));
                    float hNL = t0 + z0 * (hBL - t0);
                    float hNH = t1 + z1 * (hBH - t1);
                    hBL = hNL; hBH = hNH;
                    unsigned pk = packhi(bfr(hNL), bfr(hNH));
                    HdB[0] = QBCAST(pk, 0);
                    HdB[1] = QBCAST(pk, 1);
                    HdB[2] = QBCAST(pk, 2);
                    HdB[3] = QBCAST(pk, 3);
                }
            }
            barrier_nodrain();
        }

        // ---- head: lane holds fp32 h dims (q*4+u, +16) of batch bq, both sets
        const float w0 = W_head[q*4 + u], w1 = W_head[16 + q*4 + u];
        float vA = hAL * w0 + hAH * w1;
        float vB = hBL * w0 + hBH * w1;
        vA += __shfl_xor(vA, 1, 64);  vB += __shfl_xor(vB, 1, 64);
        vA += __shfl_xor(vA, 2, 64);  vB += __shfl_xor(vB, 2, 64);
        vA += __shfl_xor(vA, 16, 64); vB += __shfl_xor(vB, 16, 64);
        vA += __shfl_xor(vA, 32, 64); vB += __shfl_xor(vB, 32, 64);
        if (lane < 16 && (lane & 3) == 0) {
            out[b0 + (lane >> 2)]     = sigx(vA + b_head[0]);
            out[b0 + 4 + (lane >> 2)] = sigx(vB + b_head[0]);
        }
    }
}

extern "C" void kernel_launch(void* const* d_in, const int* in_sizes, int n_in,
                              void* d_out, int out_size, void* d_ws, size_t ws_size,
                              hipStream_t stream)
{
    const float* x      = (const float*)d_in[0];
    const float* W_ih   = (const float*)d_in[1];
    const float* W_hh   = (const float*)d_in[2];
    const float* b_ih   = (const float*)d_in[3];
    const float* b_hh   = (const float*)d_in[4];
    const float* W_head = (const float*)d_in[5];
    const float* b_head = (const float*)d_in[6];
    float* out = (float*)d_out;

    gru_fused<<<256, 128, 0, stream>>>(x, W_ih, W_hh, b_ih, b_hh,
                                       W_head, b_head, out);
}

// Round 7
// 220.084 us; speedup vs baseline: 1.3710x; 1.3648x over previous
//
#include <hip/hip_runtime.h>
#include <cstdint>

// Fully-fused GRU: B=2048, T=256, F=64, H=32. fp32 in/out. ONE kernel.
// 256 blocks x 256 thr = 4 waves/block (r4 structure, best measured: 95us):
//   waves 2,3 (producers, quad 0/1): ring x-loads, hi/lo bf16 split,
//     24 x-proj MFMAs/group, write LDS (double-buffered, [col][gate] layout,
//     col stride 104 floats), one group (4 steps) ahead of the chain.
//   waves 0,1 (chains, quad 0/1): recurrence with ZERO memory/LDS-latency ops
//     on the dependence chain (xp scalar reads at group top are off-chain);
//     per step 6 hh MFMAs + acts + 4x v_mov_dpp quad_perm B-frag all-gather.
// Round-7 change (trans-pipe diet; r4/r5/r6 timings triangulate ~500cy/step
// of exclusive transcendental cost — OCML exp2 fixup + trans-pipe occupancy):
//   (1) raw v_exp_f32 via __builtin_amdgcn_exp2f (no OCML denormal fixup;
//       gate pre-acts are bounded, denormal flush = correct saturation),
//   (2) batched reciprocals: 6 rcp/step -> 3 via 1/a = b*rcp(a*b) on (L,H)
//       pairs (rel err ~2^-22, invisible under bf16),
//   (3) v_cvt_pk_bf16_f32 replaces bfr+bfr+packhi on the dep chain (same RNE).
// Everything else is bit-identical to the 95us r4 kernel.

#define TSEQ 256
#define CSTRIDE 104                                // floats per col (16B aligned)

typedef __attribute__((ext_vector_type(8))) short bf16x8;
typedef __attribute__((ext_vector_type(4))) float f32x4;
union BF8 { unsigned u[4]; bf16x8 v; };

__device__ __forceinline__ unsigned bfr(float f) {            // bf16 RNE in hi16
    unsigned u = __float_as_uint(f);
    return u + 0x7fffu + ((u >> 16) & 1u);
}
__device__ __forceinline__ unsigned packhi(unsigned a, unsigned b) {
    return __builtin_amdgcn_perm(b, a, 0x07060302u);          // hi16(a)|hi16(b)<<16
}
// 8 fp32 -> hi (truncated bf16) + lo (bf16 of residual): 3-term-quality products
__device__ __forceinline__ void cvt2(const float4& f0, const float4& f1,
                                     bf16x8& hi, bf16x8& lo) {
    float f[8] = {f0.x,f0.y,f0.z,f0.w, f1.x,f1.y,f1.z,f1.w};
    BF8 H, L;
    #pragma unroll
    for (int d = 0; d < 4; ++d) {
        float a = f[2*d], b = f[2*d+1];
        unsigned ua = __float_as_uint(a), ub = __float_as_uint(b);
        float ra = a - __uint_as_float(ua & 0xffff0000u);
        float rb = b - __uint_as_float(ub & 0xffff0000u);
        H.u[d] = packhi(ua, ub);
        L.u[d] = packhi(bfr(ra), bfr(rb));
    }
    hi = H.v; lo = L.v;
}
__device__ __forceinline__ float sel4(f32x4 v, int u) {
    float a = (u & 1) ? v[1] : v[0];
    float b = (u & 1) ? v[3] : v[2];
    return (u & 2) ? b : a;
}

#define MFMA16(A, B, C) __builtin_amdgcn_mfma_f32_16x16x32_bf16((A), (B), (C), 0, 0, 0)

// quad_perm broadcast of lane w within each aligned 4-lane quad (pure VALU).
#define QBCAST(x, w) ((unsigned)__builtin_amdgcn_update_dpp( \
        0, (int)(x), ((w) | ((w)<<2) | ((w)<<4) | ((w)<<6)), 0xf, 0xf, true))

// barrier WITHOUT the compiler's vmcnt(0) drain: producers' in-flight HBM
// prefetch (needed a full group later) survives the sync.
__device__ __forceinline__ void barrier_nodrain() {
    asm volatile("s_waitcnt lgkmcnt(0)" ::: "memory");
    __builtin_amdgcn_s_barrier();
    asm volatile("" ::: "memory");
}

__global__ __launch_bounds__(256, 1)
void gru_fused(const float* __restrict__ x, const float* __restrict__ W_ih,
               const float* __restrict__ W_hh, const float* __restrict__ b_ih,
               const float* __restrict__ b_hh, const float* __restrict__ W_head,
               const float* __restrict__ b_head, float* __restrict__ out)
{
    // [buf][quad][col*CSTRIDE + nt*16 + q*4 + r]; col = batch + 4*step
    __shared__ float xsh[2][2][16 * CSTRIDE];
    const int tid  = threadIdx.x;
    const int wid  = tid >> 6;                     // 0,1 = chain; 2,3 = producer
    const int lane = tid & 63;
    const int m = lane & 15, q = lane >> 4;
    const int b0 = blockIdx.x * 8;

    if (wid >= 2) {
        // ===================== producer (quad pq) =====================
        const int pq = wid - 2;
        const int bq = m & 3, u = m >> 2;          // col m = (batch bq, step u)
        bf16x8 Aih[6][2];
        #pragma unroll
        for (int nt = 0; nt < 6; ++nt)
            #pragma unroll
            for (int c = 0; c < 2; ++c) {
                const float* wp = W_ih + (nt*16 + m)*64 + c*32 + q*8;
                BF8 t;
                #pragma unroll
                for (int d = 0; d < 4; ++d) t.u[d] = packhi(bfr(wp[2*d]), bfr(wp[2*d+1]));
                Aih[nt][c] = t.v;
            }
        float4 ring[4];
        const float* xcol = x + ((size_t)(b0 + pq*4 + bq)*TSEQ + u)*64 + q*8;
        auto ldring = [&](int grp) {
            const float* p = xcol + grp*256;       // grp*4 steps * 64 floats
            ring[0] = ((const float4*)p)[0];        ring[1] = ((const float4*)p)[1];
            ring[2] = ((const float4*)(p+32))[0];   ring[3] = ((const float4*)(p+32))[1];
        };
        auto projwrite = [&](int buf) {            // ring -> x-proj -> LDS[buf]
            bf16x8 Xh0, Xl0, Xh1, Xl1;
            cvt2(ring[0], ring[1], Xh0, Xl0);
            cvt2(ring[2], ring[3], Xh1, Xl1);
            #pragma unroll
            for (int nt = 0; nt < 6; ++nt) {
                f32x4 a = MFMA16(Aih[nt][0], Xh0, ((f32x4){0.f,0.f,0.f,0.f}));
                a = MFMA16(Aih[nt][0], Xl0, a);
                a = MFMA16(Aih[nt][1], Xh1, a);
                a = MFMA16(Aih[nt][1], Xl1, a);
                *(f32x4*)&xsh[buf][pq][m*CSTRIDE + nt*16 + q*4] = a;   // 16B aligned
            }
        };
        ldring(0);
        projwrite(0);                              // group-0 data into buf 0
        ldring(1);
        barrier_nodrain();                         // buf0 ready
        for (int g = 0; g < 64; ++g) {
            if (g < 63) {
                projwrite((g + 1) & 1);            // chain is in buf[g&1]
                ldring(g + 2 < 64 ? g + 2 : 63);
            }
            barrier_nodrain();
        }
    } else {
        // ===================== chain (quad cq) =====================
        const int cq = wid;
        const int bq = m >> 2, u = m & 3;          // replicas = consecutive lanes
        // ---- W_hh A-frags, K-permuted: pos p=q*8+j <-> dim (p>>1)+16*(p&1)
        bf16x8 Awh[6];
        #pragma unroll
        for (int nt = 0; nt < 6; ++nt) {
            const float* wp = W_hh + (nt*16 + m)*32;
            BF8 t;
            #pragma unroll
            for (int d = 0; d < 4; ++d) {
                int dd = q*4 + d;
                t.u[d] = packhi(bfr(wp[dd]), bfr(wp[dd + 16]));
            }
            Awh[nt] = t.v;
        }
        // ---- biases: C-init vectors (component reg <-> gate nt*16+q*4+reg)
        f32x4 FRZ[4], BN0, BN1;
        #pragma unroll
        for (int nt = 0; nt < 4; ++nt) {
            f32x4 t;
            #pragma unroll
            for (int r = 0; r < 4; ++r) { int g = nt*16 + q*4 + r; t[r] = b_ih[g] + b_hh[g]; }
            FRZ[nt] = t;
        }
        #pragma unroll
        for (int r = 0; r < 4; ++r) { BN0[r] = b_hh[64+q*4+r]; BN1[r] = b_hh[80+q*4+r]; }
        const float fn0 = b_ih[64 + q*4 + u], fn1 = b_ih[80 + q*4 + u];

        unsigned Hd[4] = {0u, 0u, 0u, 0u};         // h B-frag dwords (bf16 pairs)
        float hOL = 0.f, hOH = 0.f;                // own h dims (q*4+u, +16), fp32
        barrier_nodrain();                         // buf0 ready

        const float KS = -1.4426950408889634f;     // -log2(e)   (sigmoid)
        const float KT = -2.8853900817779268f;     // -2*log2(e) (tanh)
        for (int g = 0; g < 64; ++g) {
            const int cbuf = g & 1;
            // this group's x-pre scalars: 24 ds_read_b32, off the dep chain
            float xp[4][6];
            #pragma unroll
            for (int s = 0; s < 4; ++s) {
                const float* rp = &xsh[cbuf][cq][(bq + 4*s)*CSTRIDE + q*4 + u];
                #pragma unroll
                for (int nt = 0; nt < 6; ++nt) xp[s][nt] = rp[nt*16];
            }
            #pragma unroll
            for (int s = 0; s < 4; ++s) {
                BF8 bh; bh.u[0]=Hd[0]; bh.u[1]=Hd[1]; bh.u[2]=Hd[2]; bh.u[3]=Hd[3];
                f32x4 a0 = MFMA16(Awh[0], bh.v, FRZ[0]);
                f32x4 a1 = MFMA16(Awh[1], bh.v, FRZ[1]);
                f32x4 a2 = MFMA16(Awh[2], bh.v, FRZ[2]);
                f32x4 a3 = MFMA16(Awh[3], bh.v, FRZ[3]);
                f32x4 a4 = MFMA16(Awh[4], bh.v, BN0);
                f32x4 a5 = MFMA16(Awh[5], bh.v, BN1);

                // --- acts: raw v_exp, pair-batched rcp (1/a = b*rcp(ab)) ---
                float er0 = __builtin_amdgcn_exp2f(KS * (xp[s][0] + sel4(a0, u)));
                float er1 = __builtin_amdgcn_exp2f(KS * (xp[s][1] + sel4(a1, u)));
                float ez0 = __builtin_amdgcn_exp2f(KS * (xp[s][2] + sel4(a2, u)));
                float ez1 = __builtin_amdgcn_exp2f(KS * (xp[s][3] + sel4(a3, u)));
                float dr0 = 1.f + er0, dr1 = 1.f + er1;
                float dz0 = 1.f + ez0, dz1 = 1.f + ez1;
                float qr = __builtin_amdgcn_rcpf(dr0 * dr1);
                float qz = __builtin_amdgcn_rcpf(dz0 * dz1);
                float r0 = dr1 * qr, r1 = dr0 * qr;   // sigmoid(r-gates)
                float z0 = dz1 * qz, z1 = dz0 * qz;   // sigmoid(z-gates)
                float v0 = xp[s][4] + fn0 + r0 * sel4(a4, u);
                float v1 = xp[s][5] + fn1 + r1 * sel4(a5, u);
                float et0 = __builtin_amdgcn_exp2f(KT * fabsf(v0));
                float et1 = __builtin_amdgcn_exp2f(KT * fabsf(v1));
                float dt0 = 1.f + et0, dt1 = 1.f + et1;
                float qt = __builtin_amdgcn_rcpf(dt0 * dt1);
                float t0 = copysignf((1.f - et0) * dt1 * qt, v0);
                float t1 = copysignf((1.f - et1) * dt0 * qt, v1);
                float hNL = t0 + z0 * (hOL - t0);
                float hNH = t1 + z1 * (hOH - t1);
                hOL = hNL; hOH = hNH;

                // B-frag all-gather within the 4-lane replica quad (VALU only).
                unsigned pk;
                asm("v_cvt_pk_bf16_f32 %0, %1, %2" : "=v"(pk) : "v"(hNL), "v"(hNH));
                Hd[0] = QBCAST(pk, 0);
                Hd[1] = QBCAST(pk, 1);
                Hd[2] = QBCAST(pk, 2);
                Hd[3] = QBCAST(pk, 3);
            }
            barrier_nodrain();
        }

        // ---- head: lane holds fp32 h dims (q*4+u, +16) of batch bq
        float v = hOL * W_head[q*4 + u] + hOH * W_head[16 + q*4 + u];
        float s = 1.f / (1.f + __expf(-(0.f)));    // (dead; keeps no state) -- removed below
        (void)s;
        v += __shfl_xor(v, 1, 64);                 // sum over u (lane bits 0,1)
        v += __shfl_xor(v, 2, 64);
        v += __shfl_xor(v, 16, 64);                // sum over q (lane bits 4,5)
        v += __shfl_xor(v, 32, 64);
        if (lane < 16 && (lane & 3) == 0) {
            float a = v + b_head[0];
            float e = __builtin_amdgcn_exp2f(-1.4426950408889634f * a);
            out[b0 + cq*4 + (lane >> 2)] = __builtin_amdgcn_rcpf(1.f + e);
        }
    }
}

extern "C" void kernel_launch(void* const* d_in, const int* in_sizes, int n_in,
                              void* d_out, int out_size, void* d_ws, size_t ws_size,
                              hipStream_t stream)
{
    const float* x      = (const float*)d_in[0];
    const float* W_ih   = (const float*)d_in[1];
    const float* W_hh   = (const float*)d_in[2];
    const float* b_ih   = (const float*)d_in[3];
    const float* b_hh   = (const float*)d_in[4];
    const float* W_head = (const float*)d_in[5];
    const float* b_head = (const float*)d_in[6];
    float* out = (float*)d_out;

    gru_fused<<<256, 256, 0, stream>>>(x, W_ih, W_hh, b_ih, b_hh,
                                       W_head, b_head, out);
}